// Round 1
// baseline (4712.834 us; speedup 1.0000x reference)
//
#include <hip/hip_runtime.h>

#define N_INT 16384
#define N_BND 4096
#define NPTS  20480
#define DIMX  3
#define NRES  8
#define NFC   3
#define DD    128
#define Q     8            // points per wave
#define WPW   4            // waves per workgroup
#define TPB   (WPW*64)

// FMA-expand one float4 of A against 4 staged W rows into a 2-wide accumulator
#define FMA4(acc, xx)                          \
    acc[0] = fmaf(xx.x, w0.x, acc[0]);         \
    acc[0] = fmaf(xx.y, w1.x, acc[0]);         \
    acc[0] = fmaf(xx.z, w2.x, acc[0]);         \
    acc[0] = fmaf(xx.w, w3.x, acc[0]);         \
    acc[1] = fmaf(xx.x, w0.y, acc[1]);         \
    acc[1] = fmaf(xx.y, w1.y, acc[1]);         \
    acc[1] = fmaf(xx.z, w2.y, acc[1]);         \
    acc[1] = fmaf(xx.w, w3.y, acc[1]);

__global__ __launch_bounds__(TPB, 3) void pinn_main(
    const float* __restrict__ X,
    const float* __restrict__ w_first,
    const float* __restrict__ b_first,
    const float* __restrict__ W_res,
    const float* __restrict__ b_res,
    const float* __restrict__ W_last,
    const float* __restrict__ b_last,
    const float* __restrict__ lb,
    const float* __restrict__ ub,
    float* __restrict__ Fout,
    float* __restrict__ F2out)
{
    __shared__ float ldsA[WPW][3*Q*DD];   // 4 x 12 KB, wave-private regions
    const int wave = threadIdx.x >> 6;
    const int lane = threadIdx.x & 63;
    const int gw   = blockIdx.x * WPW + wave;
    const int dim  = gw / (NPTS/Q);
    const int tile = gw % (NPTS/Q);
    const int p0   = tile * Q;
    const int d0   = lane * 2;            // this lane owns features d0, d0+1

    float* A = &ldsA[wave][0];

    const float lo = lb[dim], hi = ub[dim];
    const float sc = 2.0f / (hi - lo);
    const float wf0 = w_first[dim*DD + d0];
    const float wf1 = w_first[dim*DD + d0 + 1];
    const float bf0 = b_first[dim*DD + d0];
    const float bf1 = b_first[dim*DD + d0 + 1];

    // h jet: value / d/dx / d2/dx2
    float hv[Q][2], hd[Q][2], hdd[Q][2];
#pragma unroll
    for (int q = 0; q < Q; ++q) {
        float x = X[(p0 + q)*DIMX + dim];
        float t = fmaf(x - lo, sc, -1.0f);
        hv[q][0] = fmaf(t, wf0, bf0);
        hv[q][1] = fmaf(t, wf1, bf1);
        hd[q][0] = sc*wf0;
        hd[q][1] = sc*wf1;
        hdd[q][0] = 0.f; hdd[q][1] = 0.f;
    }

    const float* Wp = W_res + (size_t)dim*(NRES*NFC*DD*DD);
    const float* bp = b_res + (size_t)dim*(NRES*NFC*DD);

    for (int r = 0; r < NRES; ++r) {
        // g = h (jet copy)
        float gv[Q][2], gd[Q][2], gdd[Q][2];
#pragma unroll
        for (int q = 0; q < Q; ++q) {
            gv[q][0]=hv[q][0];   gv[q][1]=hv[q][1];
            gd[q][0]=hd[q][0];   gd[q][1]=hd[q][1];
            gdd[q][0]=hdd[q][0]; gdd[q][1]=hdd[q][1];
        }
        for (int l = 0; l < NFC; ++l) {
            // ---- stage g jet to this wave's LDS region ----
#pragma unroll
            for (int q = 0; q < Q; ++q) {
                *(float2*)&A[(q*3+0)*DD + d0] = make_float2(gv[q][0],  gv[q][1]);
                *(float2*)&A[(q*3+1)*DD + d0] = make_float2(gd[q][0],  gd[q][1]);
                *(float2*)&A[(q*3+2)*DD + d0] = make_float2(gdd[q][0], gdd[q][1]);
            }
            __syncthreads();

            // ---- matvec: acc[d] = sum_k A[k] * W[k][d], 3 jets share W ----
            float av[Q][2] = {}, ad1[Q][2] = {}, ad2[Q][2] = {};
            const float* WL = Wp;
#pragma unroll 2
            for (int k0 = 0; k0 < DD; k0 += 4) {
                const float* wr = WL + k0*DD + d0;
                const float2 w0 = *(const float2*)(wr);
                const float2 w1 = *(const float2*)(wr + DD);
                const float2 w2 = *(const float2*)(wr + 2*DD);
                const float2 w3 = *(const float2*)(wr + 3*DD);
#pragma unroll
                for (int q = 0; q < Q; ++q) {
                    const float4 x0 = *(const float4*)&A[(q*3+0)*DD + k0];
                    const float4 x1 = *(const float4*)&A[(q*3+1)*DD + k0];
                    const float4 x2 = *(const float4*)&A[(q*3+2)*DD + k0];
                    FMA4(av[q],  x0);
                    FMA4(ad1[q], x1);
                    FMA4(ad2[q], x2);
                }
            }
            // bias (value jet only)
            const float bv0 = bp[d0], bv1 = bp[d0+1];
#pragma unroll
            for (int q = 0; q < Q; ++q) { av[q][0] += bv0; av[q][1] += bv1; }

            if (l < NFC-1) {
                // g = sin(a) jet
#pragma unroll
                for (int q = 0; q < Q; ++q) {
#pragma unroll
                    for (int i = 0; i < 2; ++i) {
                        float s = __sinf(av[q][i]);
                        float c = __cosf(av[q][i]);
                        gv[q][i]  = s;
                        gdd[q][i] = fmaf(c, ad2[q][i], -s*ad1[q][i]*ad1[q][i]);
                        gd[q][i]  = c*ad1[q][i];
                    }
                }
            } else {
                // h = sin(a + h) jet (residual)
#pragma unroll
                for (int q = 0; q < Q; ++q) {
#pragma unroll
                    for (int i = 0; i < 2; ++i) {
                        float zu = av[q][i]  + hv[q][i];
                        float z1 = ad1[q][i] + hd[q][i];
                        float z2 = ad2[q][i] + hdd[q][i];
                        float s = __sinf(zu);
                        float c = __cosf(zu);
                        hv[q][i]  = s;
                        hd[q][i]  = c*z1;
                        hdd[q][i] = fmaf(c, z2, -s*z1*z1);
                    }
                }
            }
            Wp += DD*DD;
            bp += DD;
        }
    }

    // ---- final head: F = h . W_last + b_last ; F2 = h'' . W_last ----
    const float wl0 = W_last[dim*DD + d0];
    const float wl1 = W_last[dim*DD + d0 + 1];
    const float blv = b_last[dim];
#pragma unroll
    for (int q = 0; q < Q; ++q) {
        float pv = fmaf(hv[q][0],  wl0, hv[q][1]*wl1);
        float p2 = fmaf(hdd[q][0], wl0, hdd[q][1]*wl1);
#pragma unroll
        for (int off = 32; off > 0; off >>= 1) {
            pv += __shfl_down(pv, off);
            p2 += __shfl_down(p2, off);
        }
        if (lane == 0) {
            Fout[dim*NPTS + p0 + q]  = pv + blv;
            F2out[dim*NPTS + p0 + q] = p2;
        }
    }
}

__global__ void pinn_combine(const float* __restrict__ F, const float* __restrict__ F2,
                             const float* __restrict__ rhs, float* __restrict__ out)
{
    int n = blockIdx.x*256 + threadIdx.x;
    if (n >= NPTS) return;
    float f0 = F[n], f1 = F[NPTS+n], f2 = F[2*NPTS+n];
    if (n < N_INT) {
        float lap = F2[n]*f1*f2 + F2[NPTS+n]*f0*f2 + F2[2*NPTS+n]*f0*f1;
        out[n] = -lap - rhs[n];
    } else {
        out[n] = f0*f1*f2 - rhs[n];
    }
}

extern "C" void kernel_launch(void* const* d_in, const int* in_sizes, int n_in,
                              void* d_out, int out_size, void* d_ws, size_t ws_size,
                              hipStream_t stream) {
    const float* X       = (const float*)d_in[0];
    const float* rhs     = (const float*)d_in[1];
    const float* w_first = (const float*)d_in[2];
    const float* b_first = (const float*)d_in[3];
    const float* W_res   = (const float*)d_in[4];
    const float* b_res   = (const float*)d_in[5];
    const float* W_last  = (const float*)d_in[6];
    const float* b_last  = (const float*)d_in[7];
    const float* lbv     = (const float*)d_in[8];
    const float* ubv     = (const float*)d_in[9];
    float* out = (float*)d_out;

    float* F  = (float*)d_ws;            // [3][NPTS]
    float* F2 = F + 3*NPTS;              // [3][NPTS]

    int wgs = DIMX * (NPTS/Q) / WPW;     // 1920
    pinn_main<<<wgs, TPB, 0, stream>>>(X, w_first, b_first, W_res, b_res,
                                       W_last, b_last, lbv, ubv, F, F2);
    pinn_combine<<<(NPTS+255)/256, 256, 0, stream>>>(F, F2, rhs, out);
}

// Round 2
// 1953.299 us; speedup vs baseline: 2.4128x; 2.4128x over previous
//
#include <hip/hip_runtime.h>

#define N_INT 16384
#define N_BND 4096
#define NPTS  20480
#define DIMX  3
#define NRES  8
#define NFC   3
#define DD    128
#define Q     8            // points per wave
#define WPW   4            // waves per workgroup
#define TPB   (WPW*64)

// FMA-expand one float4 of A against 4 staged W rows into a 2-wide accumulator
#define FMA4(acc, xx)                          \
    acc[0] = fmaf(xx.x, w0.x, acc[0]);         \
    acc[0] = fmaf(xx.y, w1.x, acc[0]);         \
    acc[0] = fmaf(xx.z, w2.x, acc[0]);         \
    acc[0] = fmaf(xx.w, w3.x, acc[0]);         \
    acc[1] = fmaf(xx.x, w0.y, acc[1]);         \
    acc[1] = fmaf(xx.y, w1.y, acc[1]);         \
    acc[1] = fmaf(xx.z, w2.y, acc[1]);         \
    acc[1] = fmaf(xx.w, w3.y, acc[1]);

__global__ __launch_bounds__(TPB, 2) void pinn_main(
    const float* __restrict__ X,
    const float* __restrict__ w_first,
    const float* __restrict__ b_first,
    const float* __restrict__ W_res,
    const float* __restrict__ b_res,
    const float* __restrict__ W_last,
    const float* __restrict__ b_last,
    const float* __restrict__ lb,
    const float* __restrict__ ub,
    float* __restrict__ Fout,
    float* __restrict__ F2out)
{
    __shared__ float ldsA[WPW][3*Q*DD];   // 4 x 12 KB, wave-private regions
    const int wave = threadIdx.x >> 6;
    const int lane = threadIdx.x & 63;
    const int gw   = blockIdx.x * WPW + wave;
    const int dim  = gw / (NPTS/Q);
    const int tile = gw % (NPTS/Q);
    const int p0   = tile * Q;
    const int d0   = lane * 2;            // this lane owns features d0, d0+1

    float* A = &ldsA[wave][0];

    const float lo = lb[dim], hi = ub[dim];
    const float sc = 2.0f / (hi - lo);
    const float wf0 = w_first[dim*DD + d0];
    const float wf1 = w_first[dim*DD + d0 + 1];
    const float bf0 = b_first[dim*DD + d0];
    const float bf1 = b_first[dim*DD + d0 + 1];

    // h jet: value / d/dx / d2/dx2  (persists across res-blocks; 48 VGPRs)
    float hv[Q][2], hd[Q][2], hdd[Q][2];
#pragma unroll
    for (int q = 0; q < Q; ++q) {
        float x = X[(p0 + q)*DIMX + dim];
        float t = fmaf(x - lo, sc, -1.0f);
        hv[q][0] = fmaf(t, wf0, bf0);
        hv[q][1] = fmaf(t, wf1, bf1);
        hd[q][0] = sc*wf0;
        hd[q][1] = sc*wf1;
        hdd[q][0] = 0.f; hdd[q][1] = 0.f;
    }

    const float* Wp = W_res + (size_t)dim*(NRES*NFC*DD*DD);
    const float* bp = b_res + (size_t)dim*(NRES*NFC*DD);

#pragma unroll 1
    for (int r = 0; r < NRES; ++r) {
        // ---- stage h jet into this wave's LDS region (input of layer 0) ----
#pragma unroll
        for (int q = 0; q < Q; ++q) {
            *(float2*)&A[(q*3+0)*DD + d0] = make_float2(hv[q][0],  hv[q][1]);
            *(float2*)&A[(q*3+1)*DD + d0] = make_float2(hd[q][0],  hd[q][1]);
            *(float2*)&A[(q*3+2)*DD + d0] = make_float2(hdd[q][0], hdd[q][1]);
        }

#pragma unroll 1
        for (int l = 0; l < NFC; ++l) {
            // ---- matvec: acc[d] = sum_k A[k] * W[k][d], 3 jets share W ----
            float av[Q][2] = {}, ad1[Q][2] = {}, ad2[Q][2] = {};
            const float* WL = Wp;
#pragma unroll 1
            for (int k0 = 0; k0 < DD; k0 += 4) {
                const float* wr = WL + k0*DD + d0;
                const float2 w0 = *(const float2*)(wr);
                const float2 w1 = *(const float2*)(wr + DD);
                const float2 w2 = *(const float2*)(wr + 2*DD);
                const float2 w3 = *(const float2*)(wr + 3*DD);
#pragma unroll
                for (int q = 0; q < Q; ++q) {
                    const float4 x0 = *(const float4*)&A[(q*3+0)*DD + k0];
                    const float4 x1 = *(const float4*)&A[(q*3+1)*DD + k0];
                    const float4 x2 = *(const float4*)&A[(q*3+2)*DD + k0];
                    FMA4(av[q],  x0);
                    FMA4(ad1[q], x1);
                    FMA4(ad2[q], x2);
                }
            }
            // bias (value jet only)
            const float bv0 = bp[d0], bv1 = bp[d0+1];
#pragma unroll
            for (int q = 0; q < Q; ++q) { av[q][0] += bv0; av[q][1] += bv1; }

            if (l < NFC-1) {
                // g = sin(a) jet — write straight to LDS (no register copy)
#pragma unroll
                for (int q = 0; q < Q; ++q) {
                    float nv[2], nd[2], ndd[2];
#pragma unroll
                    for (int i = 0; i < 2; ++i) {
                        float s = __sinf(av[q][i]);
                        float c = __cosf(av[q][i]);
                        nv[i]  = s;
                        ndd[i] = fmaf(c, ad2[q][i], -s*ad1[q][i]*ad1[q][i]);
                        nd[i]  = c*ad1[q][i];
                    }
                    *(float2*)&A[(q*3+0)*DD + d0] = make_float2(nv[0],  nv[1]);
                    *(float2*)&A[(q*3+1)*DD + d0] = make_float2(nd[0],  nd[1]);
                    *(float2*)&A[(q*3+2)*DD + d0] = make_float2(ndd[0], ndd[1]);
                }
            } else {
                // h = sin(a + h) jet (residual) — stays in registers
#pragma unroll
                for (int q = 0; q < Q; ++q) {
#pragma unroll
                    for (int i = 0; i < 2; ++i) {
                        float zu = av[q][i]  + hv[q][i];
                        float z1 = ad1[q][i] + hd[q][i];
                        float z2 = ad2[q][i] + hdd[q][i];
                        float s = __sinf(zu);
                        float c = __cosf(zu);
                        hv[q][i]  = s;
                        hd[q][i]  = c*z1;
                        hdd[q][i] = fmaf(c, z2, -s*z1*z1);
                    }
                }
            }
            Wp += DD*DD;
            bp += DD;
        }
    }

    // ---- final head: F = h . W_last + b_last ; F2 = h'' . W_last ----
    const float wl0 = W_last[dim*DD + d0];
    const float wl1 = W_last[dim*DD + d0 + 1];
    const float blv = b_last[dim];
#pragma unroll
    for (int q = 0; q < Q; ++q) {
        float pv = fmaf(hv[q][0],  wl0, hv[q][1]*wl1);
        float p2 = fmaf(hdd[q][0], wl0, hdd[q][1]*wl1);
#pragma unroll
        for (int off = 32; off > 0; off >>= 1) {
            pv += __shfl_down(pv, off);
            p2 += __shfl_down(p2, off);
        }
        if (lane == 0) {
            Fout[dim*NPTS + p0 + q]  = pv + blv;
            F2out[dim*NPTS + p0 + q] = p2;
        }
    }
}

__global__ void pinn_combine(const float* __restrict__ F, const float* __restrict__ F2,
                             const float* __restrict__ rhs, float* __restrict__ out)
{
    int n = blockIdx.x*256 + threadIdx.x;
    if (n >= NPTS) return;
    float f0 = F[n], f1 = F[NPTS+n], f2 = F[2*NPTS+n];
    if (n < N_INT) {
        float lap = F2[n]*f1*f2 + F2[NPTS+n]*f0*f2 + F2[2*NPTS+n]*f0*f1;
        out[n] = -lap - rhs[n];
    } else {
        out[n] = f0*f1*f2 - rhs[n];
    }
}

extern "C" void kernel_launch(void* const* d_in, const int* in_sizes, int n_in,
                              void* d_out, int out_size, void* d_ws, size_t ws_size,
                              hipStream_t stream) {
    const float* X       = (const float*)d_in[0];
    const float* rhs     = (const float*)d_in[1];
    const float* w_first = (const float*)d_in[2];
    const float* b_first = (const float*)d_in[3];
    const float* W_res   = (const float*)d_in[4];
    const float* b_res   = (const float*)d_in[5];
    const float* W_last  = (const float*)d_in[6];
    const float* b_last  = (const float*)d_in[7];
    const float* lbv     = (const float*)d_in[8];
    const float* ubv     = (const float*)d_in[9];
    float* out = (float*)d_out;

    float* F  = (float*)d_ws;            // [3][NPTS]
    float* F2 = F + 3*NPTS;              // [3][NPTS]

    int wgs = DIMX * (NPTS/Q) / WPW;     // 1920
    pinn_main<<<wgs, TPB, 0, stream>>>(X, w_first, b_first, W_res, b_res,
                                       W_last, b_last, lbv, ubv, F, F2);
    pinn_combine<<<(NPTS+255)/256, 256, 0, stream>>>(F, F2, rhs, out);
}